// Round 2
// baseline (9383.406 us; speedup 1.0000x reference)
//
#include <hip/hip_runtime.h>
#include <hip/hip_bf16.h>

#define NN 50000
#define NE 800000
#define HD 128
#define EPSV 1e-5f
#define TE 64
#define BLK 256
#define SROW 68   // padded LDS row stride (floats): 272B = 17*16 -> float4-aligned rows

__device__ __forceinline__ float sigm(float x){ return 1.0f/(1.0f+__expf(-x)); }
__device__ __forceinline__ void atomAddF(float* p, float v){ unsafeAtomicAdd(p, v); }

// ---------------- small utility kernels ----------------
__global__ void zero_f_k(float* __restrict__ p, int n){
    int i = blockIdx.x*blockDim.x + threadIdx.x;
    if (i < n) p[i] = 0.0f;
}

__global__ void zero_agg_bn_k(float4* __restrict__ agg4, int n4, float* __restrict__ bn){
    int i = blockIdx.x*blockDim.x + threadIdx.x;
    if (i < n4) agg4[i] = make_float4(0.f,0.f,0.f,0.f);
    if (i < 256) bn[i] = 0.0f;
}

__global__ void count_k(const int* __restrict__ dst, float* __restrict__ cnt){
    int e = blockIdx.x*blockDim.x + threadIdx.x;
    if (e < NE) atomAddF(&cnt[dst[e]], 1.0f);
}

__global__ void rdenom_k(const float* __restrict__ cnt, float* __restrict__ rd){
    int i = blockIdx.x*blockDim.x + threadIdx.x;
    if (i < NN) rd[i] = 1.0f / fmaxf(cnt[i], 1.0f);
}

// ---------------- shared matvec tile core ----------------
// sT[k][e] layout. Each thread: 4 edges (eg*4..) x 8 channels (c0..c0+7).
// Per k: 1 ds_read_b128 (edges) + 2 global float4 (weights, L1/L2-hot) + 32 FMA.
__device__ __forceinline__ void mv_acc(const float (*sT)[SROW], int krows,
        const float* __restrict__ W, int c0, int eg, float acc[4][8])
{
    const float* Wp = W + c0;
    #pragma unroll 2
    for (int k=0; k<krows; ++k) {
        const float4 sv = *(const float4*)&sT[k][eg*4];
        const float4 wa = *(const float4*)(Wp + k*HD);
        const float4 wb = *(const float4*)(Wp + k*HD + 4);
        const float s[4] = {sv.x, sv.y, sv.z, sv.w};
        const float w[8] = {wa.x,wa.y,wa.z,wa.w, wb.x,wb.y,wb.z,wb.w};
        #pragma unroll
        for (int i=0;i<4;++i)
            #pragma unroll
            for (int j=0;j<8;++j)
                acc[i][j] = fmaf(s[i], w[j], acc[i][j]);
    }
}

// ---------------- input MLP: h = relu(relu(x@W0+b0)@W1+b1) ----------------
__global__ __launch_bounds__(BLK) void input_mlp_k(
    const float* __restrict__ x,
    const float* __restrict__ W0, const float* __restrict__ b0,
    const float* __restrict__ W1, const float* __restrict__ b1,
    float* __restrict__ h)
{
    __shared__ float sT[132][SROW];
    const int tid = threadIdx.x;
    const int n0 = blockIdx.x * TE;

    // stage1 (K=2) computed directly into sT[c][e]
    #pragma unroll
    for (int it=0; it<(HD*TE)/BLK; ++it) {
        int task = it*BLK + tid;
        int e = task & (TE-1);
        int c = task >> 6;
        int n = n0 + e; if (n >= NN) n = NN-1;
        float x0 = x[n*2+0], x1 = x[n*2+1];
        sT[c][e] = fmaxf(fmaf(x0, W0[c], fmaf(x1, W0[HD+c], b0[c])), 0.0f);
    }
    __syncthreads();

    const int cg = tid & 15, eg = tid >> 4, c0 = cg*8;
    float acc[4][8];
    #pragma unroll
    for (int j=0;j<8;++j){ float bv=b1[c0+j];
        #pragma unroll
        for (int i=0;i<4;++i) acc[i][j]=bv; }
    mv_acc(sT, HD, W1, c0, eg, acc);

    #pragma unroll
    for (int i=0;i<4;++i){
        int n = n0 + eg*4 + i;
        if (n < NN) {
            float4 r0, r1;
            r0.x=fmaxf(acc[i][0],0.f); r0.y=fmaxf(acc[i][1],0.f);
            r0.z=fmaxf(acc[i][2],0.f); r0.w=fmaxf(acc[i][3],0.f);
            r1.x=fmaxf(acc[i][4],0.f); r1.y=fmaxf(acc[i][5],0.f);
            r1.z=fmaxf(acc[i][6],0.f); r1.w=fmaxf(acc[i][7],0.f);
            *(float4*)&h[(size_t)n*HD + c0]     = r0;
            *(float4*)&h[(size_t)n*HD + c0 + 4] = r1;
        }
    }
}

// ---------------- edge kernel: m = relu(W1b·relu(W1a·[h_src;ea]+b1a)+b1b); agg[dst]+=m ----
__global__ __launch_bounds__(BLK) void edge_kernel(
    const float* __restrict__ h, const float* __restrict__ ea,
    const int* __restrict__ src, const int* __restrict__ dst,
    const float* __restrict__ W1a, const float* __restrict__ b1a,
    const float* __restrict__ W1b, const float* __restrict__ b1b,
    float* __restrict__ agg)
{
    __shared__ float sT[132][SROW];
    __shared__ int sidx[2][TE];
    const int tid = threadIdx.x;
    const int e0 = blockIdx.x * TE;

    if (tid < TE) {
        sidx[0][tid] = src[e0 + tid];
        sidx[1][tid] = dst[e0 + tid];
    }
    __syncthreads();

    // stage gathered h[src] transposed: rows 0..127; edge_attr rows 128..129
    {
        const int e_lo = tid>>3, kq = tid&7;
        const int r0 = sidx[0][e_lo], r1 = sidx[0][e_lo+32];
        #pragma unroll
        for (int half=0; half<2; ++half) {
            const int e = e_lo + 32*half;
            const int row = half ? r1 : r0;
            const float* hp = h + (size_t)row*HD + kq*4;
            #pragma unroll
            for (int q=0; q<4; ++q) {
                const float4 v = *(const float4*)(hp + q*32);
                const int kb = 4*kq + 32*q;
                sT[kb+0][e]=v.x; sT[kb+1][e]=v.y; sT[kb+2][e]=v.z; sT[kb+3][e]=v.w;
            }
        }
        if (tid < TE) {
            float2 a = *(const float2*)&ea[(size_t)(e0+tid)*2];
            sT[128][tid]=a.x; sT[129][tid]=a.y;
        }
    }
    __syncthreads();

    const int cg = tid & 15, eg = tid >> 4, c0 = cg*8;

    float acc[4][8];
    #pragma unroll
    for (int j=0;j<8;++j){ float bv=b1a[c0+j];
        #pragma unroll
        for (int i=0;i<4;++i) acc[i][j]=bv; }
    mv_acc(sT, HD+2, W1a, c0, eg, acc);
    __syncthreads();

    // write m1T = relu(acc) back into sT rows 0..127
    #pragma unroll
    for (int j=0;j<8;++j){
        float4 m0;
        m0.x=fmaxf(acc[0][j],0.f); m0.y=fmaxf(acc[1][j],0.f);
        m0.z=fmaxf(acc[2][j],0.f); m0.w=fmaxf(acc[3][j],0.f);
        *(float4*)&sT[c0+j][eg*4] = m0;
    }
    __syncthreads();

    float acc2[4][8];
    #pragma unroll
    for (int j=0;j<8;++j){ float bv=b1b[c0+j];
        #pragma unroll
        for (int i=0;i<4;++i) acc2[i][j]=bv; }
    mv_acc(sT, HD, W1b, c0, eg, acc2);

    // scatter with hardware f32 atomics
    #pragma unroll
    for (int i=0;i<4;++i){
        const int d = sidx[1][eg*4+i];
        float* ap = &agg[(size_t)d*HD + c0];
        #pragma unroll
        for (int j=0;j<8;++j)
            atomAddF(ap + j, fmaxf(acc2[i][j], 0.f));
    }
}

// ---------------- node kernel: r = h + sigmoid(W2b·relu(W2a·[h;agg/deg]+b2a)+b2b) ----
__global__ __launch_bounds__(BLK) void node_kernel(
    const float* __restrict__ h, const float* __restrict__ agg,
    const float* __restrict__ rdenom,
    const float* __restrict__ W2a, const float* __restrict__ b2a,
    const float* __restrict__ W2b, const float* __restrict__ b2b,
    float* __restrict__ rbuf)
{
    __shared__ float sT[132][SROW];
    const int tid = threadIdx.x;
    const int n0 = blockIdx.x * TE;
    const int cg = tid & 15, eg = tid >> 4, c0 = cg*8;

    // stage h rows
    {
        const int e_lo = tid>>3, kq = tid&7;
        #pragma unroll
        for (int half=0; half<2; ++half) {
            const int e = e_lo + 32*half;
            int n = n0 + e; if (n >= NN) n = NN-1;
            const float* hp = h + (size_t)n*HD + kq*4;
            #pragma unroll
            for (int q=0; q<4; ++q) {
                const float4 v = *(const float4*)(hp + q*32);
                const int kb = 4*kq + 32*q;
                sT[kb+0][e]=v.x; sT[kb+1][e]=v.y; sT[kb+2][e]=v.z; sT[kb+3][e]=v.w;
            }
        }
    }
    __syncthreads();

    float acc[4][8];
    #pragma unroll
    for (int j=0;j<8;++j){ float bv=b2a[c0+j];
        #pragma unroll
        for (int i=0;i<4;++i) acc[i][j]=bv; }
    mv_acc(sT, HD, W2a, c0, eg, acc);   // first half of K=256
    __syncthreads();

    // stage agg*rdenom into same rows
    {
        const int e_lo = tid>>3, kq = tid&7;
        #pragma unroll
        for (int half=0; half<2; ++half) {
            const int e = e_lo + 32*half;
            int n = n0 + e; if (n >= NN) n = NN-1;
            const float rdv = rdenom[n];
            const float* ap = agg + (size_t)n*HD + kq*4;
            #pragma unroll
            for (int q=0; q<4; ++q) {
                const float4 v = *(const float4*)(ap + q*32);
                const int kb = 4*kq + 32*q;
                sT[kb+0][e]=v.x*rdv; sT[kb+1][e]=v.y*rdv; sT[kb+2][e]=v.z*rdv; sT[kb+3][e]=v.w*rdv;
            }
        }
    }
    __syncthreads();
    mv_acc(sT, HD, W2a + HD*HD, c0, eg, acc);  // second half (rows 128..255 of W2a)
    __syncthreads();

    // uT = relu(acc) into sT rows 0..127
    #pragma unroll
    for (int j=0;j<8;++j){
        float4 m0;
        m0.x=fmaxf(acc[0][j],0.f); m0.y=fmaxf(acc[1][j],0.f);
        m0.z=fmaxf(acc[2][j],0.f); m0.w=fmaxf(acc[3][j],0.f);
        *(float4*)&sT[c0+j][eg*4] = m0;
    }
    __syncthreads();

    float acc2[4][8];
    #pragma unroll
    for (int j=0;j<8;++j){ float bv=b2b[c0+j];
        #pragma unroll
        for (int i=0;i<4;++i) acc2[i][j]=bv; }
    mv_acc(sT, HD, W2b, c0, eg, acc2);

    // r = h + sigmoid(acc2); store
    #pragma unroll
    for (int i=0;i<4;++i){
        const int n = n0 + eg*4 + i;
        if (n < NN) {
            const float4 h0 = *(const float4*)&h[(size_t)n*HD + c0];
            const float4 h1 = *(const float4*)&h[(size_t)n*HD + c0 + 4];
            float4 r0, r1;
            r0.x = h0.x + sigm(acc2[i][0]); r0.y = h0.y + sigm(acc2[i][1]);
            r0.z = h0.z + sigm(acc2[i][2]); r0.w = h0.w + sigm(acc2[i][3]);
            r1.x = h1.x + sigm(acc2[i][4]); r1.y = h1.y + sigm(acc2[i][5]);
            r1.z = h1.z + sigm(acc2[i][6]); r1.w = h1.w + sigm(acc2[i][7]);
            *(float4*)&rbuf[(size_t)n*HD + c0]     = r0;
            *(float4*)&rbuf[(size_t)n*HD + c0 + 4] = r1;
        }
    }
}

// ---------------- BN stats: bn[c]=sum, bn[128+c]=sumsq ----------------
__global__ void bn_stats_k(const float* __restrict__ r, float* __restrict__ bn){
    const int c = threadIdx.x & (HD-1);
    const int half = threadIdx.x >> 7;
    const int stride = gridDim.x * 2;
    float s = 0.f, ss = 0.f;
    for (int n = blockIdx.x*2 + half; n < NN; n += stride) {
        const float v = r[(size_t)n*HD + c];
        s += v; ss += v*v;
    }
    atomAddF(&bn[c], s);
    atomAddF(&bn[HD+c], ss);
}

// ---------------- BN normalize: h = (r-mu)*rsqrt(var+eps)*gamma+beta ----------------
__global__ void bn_norm_k(const float* __restrict__ r, const float* __restrict__ bn,
                          const float* __restrict__ gamma, const float* __restrict__ beta,
                          float* __restrict__ h){
    const int i = blockIdx.x*blockDim.x + threadIdx.x;  // float4 index
    const int n4 = NN*HD/4;
    if (i >= n4) return;
    const int c0 = (i*4) & (HD-1);
    float4 v = ((const float4*)r)[i];
    float* vp = (float*)&v;
    #pragma unroll
    for (int j=0;j<4;++j){
        const int c = c0 + j;
        const float mu  = bn[c] * (1.0f/NN);
        const float var = bn[HD+c] * (1.0f/NN) - mu*mu;
        const float sc  = rsqrtf(var + EPSV) * gamma[c];
        const float sh  = beta[c] - mu*sc;
        vp[j] = fmaf(vp[j], sc, sh);
    }
    ((float4*)h)[i] = v;
}

// ---------------- final MLP: out = sigmoid(relu(h@Wf+bf)@Wo+bo) ----------------
__global__ __launch_bounds__(BLK) void final_kernel(
    const float* __restrict__ h,
    const float* __restrict__ Wf, const float* __restrict__ bf,
    const float* __restrict__ Wo, const float* __restrict__ bo,
    float* __restrict__ out)
{
    __shared__ float sT[132][SROW];
    const int tid = threadIdx.x;
    const int n0 = blockIdx.x * TE;
    const int cg = tid & 15, eg = tid >> 4, c0 = cg*8;

    {
        const int e_lo = tid>>3, kq = tid&7;
        #pragma unroll
        for (int half=0; half<2; ++half) {
            const int e = e_lo + 32*half;
            int n = n0 + e; if (n >= NN) n = NN-1;
            const float* hp = h + (size_t)n*HD + kq*4;
            #pragma unroll
            for (int q=0; q<4; ++q) {
                const float4 v = *(const float4*)(hp + q*32);
                const int kb = 4*kq + 32*q;
                sT[kb+0][e]=v.x; sT[kb+1][e]=v.y; sT[kb+2][e]=v.z; sT[kb+3][e]=v.w;
            }
        }
    }
    __syncthreads();

    float acc[4][8];
    #pragma unroll
    for (int j=0;j<8;++j){ float bv=bf[c0+j];
        #pragma unroll
        for (int i=0;i<4;++i) acc[i][j]=bv; }
    mv_acc(sT, HD, Wf, c0, eg, acc);
    __syncthreads();

    #pragma unroll
    for (int j=0;j<8;++j){
        float4 m0;
        m0.x=fmaxf(acc[0][j],0.f); m0.y=fmaxf(acc[1][j],0.f);
        m0.z=fmaxf(acc[2][j],0.f); m0.w=fmaxf(acc[3][j],0.f);
        *(float4*)&sT[c0+j][eg*4] = m0;
    }
    __syncthreads();

    // out[n] = sigmoid(dot(f[n], Wo) + bo)
    const int e = tid >> 2, q = tid & 3;
    float s = 0.f;
    #pragma unroll
    for (int kk=0; kk<32; ++kk) {
        const int k = q*32 + kk;
        s = fmaf(sT[k][e], Wo[k], s);
    }
    s += __shfl_xor(s, 1);
    s += __shfl_xor(s, 2);
    const int n = n0 + e;
    if (q == 0 && n < NN)
        out[n] = sigm(s + bo[0]);
}

// ---------------- launch ----------------
extern "C" void kernel_launch(void* const* d_in, const int* in_sizes, int n_in,
                              void* d_out, int out_size, void* d_ws, size_t ws_size,
                              hipStream_t stream)
{
    const float* x    = (const float*)d_in[0];
    const float* ea   = (const float*)d_in[1];
    const int*   ei   = (const int*)d_in[2];
    const float* Win0 = (const float*)d_in[4];
    const float* bin0 = (const float*)d_in[5];
    const float* Win1 = (const float*)d_in[6];
    const float* bin1 = (const float*)d_in[7];
    const float* W1a  = (const float*)d_in[8];
    const float* b1a  = (const float*)d_in[9];
    const float* W1b  = (const float*)d_in[10];
    const float* b1b  = (const float*)d_in[11];
    const float* W2a  = (const float*)d_in[12];
    const float* b2a  = (const float*)d_in[13];
    const float* W2b  = (const float*)d_in[14];
    const float* b2b  = (const float*)d_in[15];
    const float* gmm  = (const float*)d_in[16];
    const float* bta  = (const float*)d_in[17];
    const float* Wf   = (const float*)d_in[18];
    const float* bfv  = (const float*)d_in[19];
    const float* Wo   = (const float*)d_in[20];
    const float* bo   = (const float*)d_in[21];
    float* out = (float*)d_out;

    float* ws   = (float*)d_ws;
    float* h    = ws;                          // NN*HD
    float* rbuf = h    + (size_t)NN*HD;        // NN*HD
    float* agg  = rbuf + (size_t)NN*HD;        // NN*HD
    float* cnt  = agg  + (size_t)NN*HD;        // NN
    float* rd   = cnt  + NN;                   // NN
    float* bn   = rd   + NN;                   // 256

    const int* srcp = ei;
    const int* dstp = ei + NE;

    const int GN = (NN + TE - 1) / TE;     // 782
    const int GE = NE / TE;                // 12500
    const int G4 = (NN*HD/4 + 255) / 256;  // 6250

    zero_f_k<<<(NN+255)/256, 256, 0, stream>>>(cnt, NN);
    count_k<<<(NE+255)/256, 256, 0, stream>>>(dstp, cnt);
    rdenom_k<<<(NN+255)/256, 256, 0, stream>>>(cnt, rd);
    input_mlp_k<<<GN, BLK, 0, stream>>>(x, Win0, bin0, Win1, bin1, h);

    for (int l = 0; l < 3; ++l) {
        zero_agg_bn_k<<<G4, 256, 0, stream>>>((float4*)agg, NN*HD/4, bn);
        edge_kernel<<<GE, BLK, 0, stream>>>(h, ea, srcp, dstp,
            W1a + (size_t)l*(HD+2)*HD, b1a + l*HD,
            W1b + (size_t)l*HD*HD,     b1b + l*HD, agg);
        node_kernel<<<GN, BLK, 0, stream>>>(h, agg, rd,
            W2a + (size_t)l*2*HD*HD, b2a + l*HD,
            W2b + (size_t)l*HD*HD,   b2b + l*HD, rbuf);
        bn_stats_k<<<400, 256, 0, stream>>>(rbuf, bn);
        bn_norm_k<<<G4, 256, 0, stream>>>(rbuf, bn, gmm + l*HD, bta + l*HD, h);
    }

    final_kernel<<<GN, BLK, 0, stream>>>(h, Wf, bfv, Wo, bo, out);
}

// Round 3
// 4771.083 us; speedup vs baseline: 1.9667x; 1.9667x over previous
//
#include <hip/hip_runtime.h>
#include <hip/hip_bf16.h>

#define NN 50000
#define NE 800000
#define HD 128
#define EPSV 1e-5f
#define TE 64
#define BLK 256
#define SROW 68   // padded LDS row stride (floats): 272B -> float4-aligned rows

__device__ __forceinline__ float sigm(float x){ return 1.0f/(1.0f+__expf(-x)); }
__device__ __forceinline__ void atomAddF(float* p, float v){ unsafeAtomicAdd(p, v); }

// ---------------- small utility kernels ----------------
__global__ void zero_i_k(int* __restrict__ p, int n){
    int i = blockIdx.x*blockDim.x + threadIdx.x;
    if (i < n) p[i] = 0;
}

__global__ void zero_agg_bn_k(float4* __restrict__ agg4, int n4, float* __restrict__ bn){
    int i = blockIdx.x*blockDim.x + threadIdx.x;
    if (i < n4) agg4[i] = make_float4(0.f,0.f,0.f,0.f);
    if (i < 256) bn[i] = 0.0f;
}

__global__ void count_k(const int* __restrict__ dst, int* __restrict__ cnt){
    int e = blockIdx.x*blockDim.x + threadIdx.x;
    if (e < NE) atomicAdd(&cnt[dst[e]], 1);
}

__global__ void rdenom_k(const int* __restrict__ cnt, float* __restrict__ rd){
    int i = blockIdx.x*blockDim.x + threadIdx.x;
    if (i < NN) rd[i] = 1.0f / fmaxf((float)cnt[i], 1.0f);
}

// single-block exclusive scan over NN ints (degree histogram -> CSR offsets)
__global__ __launch_bounds__(1024) void scan_k(const int* __restrict__ cnt, int* __restrict__ off){
    __shared__ int s[1024];
    __shared__ int carryS;
    const int tid = threadIdx.x;
    if (tid == 0) carryS = 0;
    __syncthreads();
    const int NCH = (NN + 1023) / 1024;
    for (int ch = 0; ch < NCH; ++ch){
        const int i = ch*1024 + tid;
        const int v = (i < NN) ? cnt[i] : 0;
        s[tid] = v;
        __syncthreads();
        #pragma unroll
        for (int ofs = 1; ofs < 1024; ofs <<= 1){
            int t = (tid >= ofs) ? s[tid-ofs] : 0;
            __syncthreads();
            s[tid] += t;
            __syncthreads();
        }
        const int carry = carryS;
        if (i < NN) off[i] = carry + s[tid] - v;  // exclusive
        __syncthreads();
        if (tid == 1023) carryS = carry + s[1023];
        __syncthreads();
    }
}

// bucket-fill: slot ordering within a node is arbitrary (sum order doesn't matter)
__global__ void fill_k(const int* __restrict__ dst, const int* __restrict__ off,
                       int* __restrict__ fill, int* __restrict__ eidx, int* __restrict__ sdst){
    int e = blockIdx.x*blockDim.x + threadIdx.x;
    if (e < NE){
        int d = dst[e];
        int pos = atomicAdd(&fill[d], 1);
        int slot = off[d] + pos;
        eidx[slot] = e;
        sdst[slot] = d;
    }
}

// ---------------- shared matvec tile core ----------------
// sT[k][e] layout. Each thread: 4 edges (eg*4..) x 8 channels (c0..c0+7).
__device__ __forceinline__ void mv_acc(const float (*sT)[SROW], int krows,
        const float* __restrict__ W, int c0, int eg, float acc[4][8])
{
    const float* Wp = W + c0;
    #pragma unroll 2
    for (int k=0; k<krows; ++k) {
        const float4 sv = *(const float4*)&sT[k][eg*4];
        const float4 wa = *(const float4*)(Wp + k*HD);
        const float4 wb = *(const float4*)(Wp + k*HD + 4);
        const float s[4] = {sv.x, sv.y, sv.z, sv.w};
        const float w[8] = {wa.x,wa.y,wa.z,wa.w, wb.x,wb.y,wb.z,wb.w};
        #pragma unroll
        for (int i=0;i<4;++i)
            #pragma unroll
            for (int j=0;j<8;++j)
                acc[i][j] = fmaf(s[i], w[j], acc[i][j]);
    }
}

// ---------------- input MLP: h = relu(relu(x@W0+b0)@W1+b1) ----------------
__global__ __launch_bounds__(BLK) void input_mlp_k(
    const float* __restrict__ x,
    const float* __restrict__ W0, const float* __restrict__ b0,
    const float* __restrict__ W1, const float* __restrict__ b1,
    float* __restrict__ h)
{
    __shared__ float sT[132][SROW];
    const int tid = threadIdx.x;
    const int n0 = blockIdx.x * TE;

    #pragma unroll
    for (int it=0; it<(HD*TE)/BLK; ++it) {
        int task = it*BLK + tid;
        int e = task & (TE-1);
        int c = task >> 6;
        int n = n0 + e; if (n >= NN) n = NN-1;
        float x0 = x[n*2+0], x1 = x[n*2+1];
        sT[c][e] = fmaxf(fmaf(x0, W0[c], fmaf(x1, W0[HD+c], b0[c])), 0.0f);
    }
    __syncthreads();

    const int cg = tid & 15, eg = tid >> 4, c0 = cg*8;
    float acc[4][8];
    #pragma unroll
    for (int j=0;j<8;++j){ float bv=b1[c0+j];
        #pragma unroll
        for (int i=0;i<4;++i) acc[i][j]=bv; }
    mv_acc(sT, HD, W1, c0, eg, acc);

    #pragma unroll
    for (int i=0;i<4;++i){
        int n = n0 + eg*4 + i;
        if (n < NN) {
            float4 r0, r1;
            r0.x=fmaxf(acc[i][0],0.f); r0.y=fmaxf(acc[i][1],0.f);
            r0.z=fmaxf(acc[i][2],0.f); r0.w=fmaxf(acc[i][3],0.f);
            r1.x=fmaxf(acc[i][4],0.f); r1.y=fmaxf(acc[i][5],0.f);
            r1.z=fmaxf(acc[i][6],0.f); r1.w=fmaxf(acc[i][7],0.f);
            *(float4*)&h[(size_t)n*HD + c0]     = r0;
            *(float4*)&h[(size_t)n*HD + c0 + 4] = r1;
        }
    }
}

// ---- edge kernel (dst-sorted): m = relu(W1b·relu(W1a·[h_src;ea]+b1a)+b1b); agg[dst]+=m ----
__global__ __launch_bounds__(BLK) void edge_kernel(
    const float* __restrict__ h, const float* __restrict__ ea,
    const int* __restrict__ src,
    const int* __restrict__ eidx, const int* __restrict__ sdst,
    const float* __restrict__ W1a, const float* __restrict__ b1a,
    const float* __restrict__ W1b, const float* __restrict__ b1b,
    float* __restrict__ agg)
{
    __shared__ float sT[132][SROW];
    __shared__ int sidx[2][TE];   // [0]=src node of sorted edge, [1]=dst
    const int tid = threadIdx.x;
    const int e0 = blockIdx.x * TE;

    if (tid < TE) {
        const int et = eidx[e0 + tid];
        sidx[0][tid] = src[et];
        sidx[1][tid] = sdst[e0 + tid];
        const float2 a = *(const float2*)&ea[(size_t)et*2];
        sT[128][tid] = a.x; sT[129][tid] = a.y;
    }
    __syncthreads();

    // stage gathered h[src] transposed into rows 0..127
    {
        const int e_lo = tid>>3, kq = tid&7;
        const int r0 = sidx[0][e_lo], r1 = sidx[0][e_lo+32];
        #pragma unroll
        for (int half=0; half<2; ++half) {
            const int e = e_lo + 32*half;
            const int row = half ? r1 : r0;
            const float* hp = h + (size_t)row*HD + kq*4;
            #pragma unroll
            for (int q=0; q<4; ++q) {
                const float4 v = *(const float4*)(hp + q*32);
                const int kb = 4*kq + 32*q;
                sT[kb+0][e]=v.x; sT[kb+1][e]=v.y; sT[kb+2][e]=v.z; sT[kb+3][e]=v.w;
            }
        }
    }
    __syncthreads();

    const int cg = tid & 15, eg = tid >> 4, c0 = cg*8;

    float acc[4][8];
    #pragma unroll
    for (int j=0;j<8;++j){ float bv=b1a[c0+j];
        #pragma unroll
        for (int i=0;i<4;++i) acc[i][j]=bv; }
    mv_acc(sT, HD+2, W1a, c0, eg, acc);
    __syncthreads();

    // m1T = relu(acc) back into sT rows 0..127
    #pragma unroll
    for (int j=0;j<8;++j){
        float4 m0;
        m0.x=fmaxf(acc[0][j],0.f); m0.y=fmaxf(acc[1][j],0.f);
        m0.z=fmaxf(acc[2][j],0.f); m0.w=fmaxf(acc[3][j],0.f);
        *(float4*)&sT[c0+j][eg*4] = m0;
    }
    __syncthreads();

    float acc2[4][8];
    #pragma unroll
    for (int j=0;j<8;++j){ float bv=b1b[c0+j];
        #pragma unroll
        for (int i=0;i<4;++i) acc2[i][j]=bv; }
    mv_acc(sT, HD, W1b, c0, eg, acc2);

    // register-level segment reduction over this thread's 4 consecutive sorted edges,
    // then one 8-channel atomic burst per distinct dst
    {
        int dprev = sidx[1][eg*4];
        float v[8];
        #pragma unroll
        for (int j=0;j<8;++j) v[j] = fmaxf(acc2[0][j], 0.f);
        #pragma unroll
        for (int i=1;i<4;++i){
            const int d = sidx[1][eg*4+i];
            if (d == dprev) {
                #pragma unroll
                for (int j=0;j<8;++j) v[j] += fmaxf(acc2[i][j], 0.f);
            } else {
                float* ap = &agg[(size_t)dprev*HD + c0];
                #pragma unroll
                for (int j=0;j<8;++j) atomAddF(ap+j, v[j]);
                dprev = d;
                #pragma unroll
                for (int j=0;j<8;++j) v[j] = fmaxf(acc2[i][j], 0.f);
            }
        }
        float* ap = &agg[(size_t)dprev*HD + c0];
        #pragma unroll
        for (int j=0;j<8;++j) atomAddF(ap+j, v[j]);
    }
}

// ---------------- node kernel: r = h + sigmoid(W2b·relu(W2a·[h;agg/deg]+b2a)+b2b) ----
__global__ __launch_bounds__(BLK) void node_kernel(
    const float* __restrict__ h, const float* __restrict__ agg,
    const float* __restrict__ rdenom,
    const float* __restrict__ W2a, const float* __restrict__ b2a,
    const float* __restrict__ W2b, const float* __restrict__ b2b,
    float* __restrict__ rbuf)
{
    __shared__ float sT[132][SROW];
    const int tid = threadIdx.x;
    const int n0 = blockIdx.x * TE;
    const int cg = tid & 15, eg = tid >> 4, c0 = cg*8;

    // stage h rows
    {
        const int e_lo = tid>>3, kq = tid&7;
        #pragma unroll
        for (int half=0; half<2; ++half) {
            const int e = e_lo + 32*half;
            int n = n0 + e; if (n >= NN) n = NN-1;
            const float* hp = h + (size_t)n*HD + kq*4;
            #pragma unroll
            for (int q=0; q<4; ++q) {
                const float4 v = *(const float4*)(hp + q*32);
                const int kb = 4*kq + 32*q;
                sT[kb+0][e]=v.x; sT[kb+1][e]=v.y; sT[kb+2][e]=v.z; sT[kb+3][e]=v.w;
            }
        }
    }
    __syncthreads();

    float acc[4][8];
    #pragma unroll
    for (int j=0;j<8;++j){ float bv=b2a[c0+j];
        #pragma unroll
        for (int i=0;i<4;++i) acc[i][j]=bv; }
    mv_acc(sT, HD, W2a, c0, eg, acc);   // first half of K=256
    __syncthreads();

    // stage agg*rdenom
    {
        const int e_lo = tid>>3, kq = tid&7;
        #pragma unroll
        for (int half=0; half<2; ++half) {
            const int e = e_lo + 32*half;
            int n = n0 + e; if (n >= NN) n = NN-1;
            const float rdv = rdenom[n];
            const float* ap = agg + (size_t)n*HD + kq*4;
            #pragma unroll
            for (int q=0; q<4; ++q) {
                const float4 v = *(const float4*)(ap + q*32);
                const int kb = 4*kq + 32*q;
                sT[kb+0][e]=v.x*rdv; sT[kb+1][e]=v.y*rdv; sT[kb+2][e]=v.z*rdv; sT[kb+3][e]=v.w*rdv;
            }
        }
    }
    __syncthreads();
    mv_acc(sT, HD, W2a + HD*HD, c0, eg, acc);  // second half (rows 128..255 of W2a)
    __syncthreads();

    // uT = relu(acc)
    #pragma unroll
    for (int j=0;j<8;++j){
        float4 m0;
        m0.x=fmaxf(acc[0][j],0.f); m0.y=fmaxf(acc[1][j],0.f);
        m0.z=fmaxf(acc[2][j],0.f); m0.w=fmaxf(acc[3][j],0.f);
        *(float4*)&sT[c0+j][eg*4] = m0;
    }
    __syncthreads();

    float acc2[4][8];
    #pragma unroll
    for (int j=0;j<8;++j){ float bv=b2b[c0+j];
        #pragma unroll
        for (int i=0;i<4;++i) acc2[i][j]=bv; }
    mv_acc(sT, HD, W2b, c0, eg, acc2);

    #pragma unroll
    for (int i=0;i<4;++i){
        const int n = n0 + eg*4 + i;
        if (n < NN) {
            const float4 h0 = *(const float4*)&h[(size_t)n*HD + c0];
            const float4 h1 = *(const float4*)&h[(size_t)n*HD + c0 + 4];
            float4 r0, r1;
            r0.x = h0.x + sigm(acc2[i][0]); r0.y = h0.y + sigm(acc2[i][1]);
            r0.z = h0.z + sigm(acc2[i][2]); r0.w = h0.w + sigm(acc2[i][3]);
            r1.x = h1.x + sigm(acc2[i][4]); r1.y = h1.y + sigm(acc2[i][5]);
            r1.z = h1.z + sigm(acc2[i][6]); r1.w = h1.w + sigm(acc2[i][7]);
            *(float4*)&rbuf[(size_t)n*HD + c0]     = r0;
            *(float4*)&rbuf[(size_t)n*HD + c0 + 4] = r1;
        }
    }
}

// ---------------- BN stats: bn[c]=sum, bn[128+c]=sumsq ----------------
__global__ void bn_stats_k(const float* __restrict__ r, float* __restrict__ bn){
    const int c = threadIdx.x & (HD-1);
    const int half = threadIdx.x >> 7;
    const int stride = gridDim.x * 2;
    float s = 0.f, ss = 0.f;
    for (int n = blockIdx.x*2 + half; n < NN; n += stride) {
        const float v = r[(size_t)n*HD + c];
        s += v; ss += v*v;
    }
    atomAddF(&bn[c], s);
    atomAddF(&bn[HD+c], ss);
}

// ---------------- BN normalize ----------------
__global__ void bn_norm_k(const float* __restrict__ r, const float* __restrict__ bn,
                          const float* __restrict__ gamma, const float* __restrict__ beta,
                          float* __restrict__ h){
    const int i = blockIdx.x*blockDim.x + threadIdx.x;  // float4 index
    const int n4 = NN*HD/4;
    if (i >= n4) return;
    const int c0 = (i*4) & (HD-1);
    float4 v = ((const float4*)r)[i];
    float* vp = (float*)&v;
    #pragma unroll
    for (int j=0;j<4;++j){
        const int c = c0 + j;
        const float mu  = bn[c] * (1.0f/NN);
        const float var = bn[HD+c] * (1.0f/NN) - mu*mu;
        const float sc  = rsqrtf(var + EPSV) * gamma[c];
        const float sh  = beta[c] - mu*sc;
        vp[j] = fmaf(vp[j], sc, sh);
    }
    ((float4*)h)[i] = v;
}

// ---------------- final MLP ----------------
__global__ __launch_bounds__(BLK) void final_kernel(
    const float* __restrict__ h,
    const float* __restrict__ Wf, const float* __restrict__ bf,
    const float* __restrict__ Wo, const float* __restrict__ bo,
    float* __restrict__ out)
{
    __shared__ float sT[132][SROW];
    const int tid = threadIdx.x;
    const int n0 = blockIdx.x * TE;
    const int cg = tid & 15, eg = tid >> 4, c0 = cg*8;

    {
        const int e_lo = tid>>3, kq = tid&7;
        #pragma unroll
        for (int half=0; half<2; ++half) {
            const int e = e_lo + 32*half;
            int n = n0 + e; if (n >= NN) n = NN-1;
            const float* hp = h + (size_t)n*HD + kq*4;
            #pragma unroll
            for (int q=0; q<4; ++q) {
                const float4 v = *(const float4*)(hp + q*32);
                const int kb = 4*kq + 32*q;
                sT[kb+0][e]=v.x; sT[kb+1][e]=v.y; sT[kb+2][e]=v.z; sT[kb+3][e]=v.w;
            }
        }
    }
    __syncthreads();

    float acc[4][8];
    #pragma unroll
    for (int j=0;j<8;++j){ float bv=bf[c0+j];
        #pragma unroll
        for (int i=0;i<4;++i) acc[i][j]=bv; }
    mv_acc(sT, HD, Wf, c0, eg, acc);
    __syncthreads();

    #pragma unroll
    for (int j=0;j<8;++j){
        float4 m0;
        m0.x=fmaxf(acc[0][j],0.f); m0.y=fmaxf(acc[1][j],0.f);
        m0.z=fmaxf(acc[2][j],0.f); m0.w=fmaxf(acc[3][j],0.f);
        *(float4*)&sT[c0+j][eg*4] = m0;
    }
    __syncthreads();

    const int e = tid >> 2, q = tid & 3;
    float s = 0.f;
    #pragma unroll
    for (int kk=0; kk<32; ++kk) {
        const int k = q*32 + kk;
        s = fmaf(sT[k][e], Wo[k], s);
    }
    s += __shfl_xor(s, 1);
    s += __shfl_xor(s, 2);
    const int n = n0 + e;
    if (q == 0 && n < NN)
        out[n] = sigm(s + bo[0]);
}

// ---------------- launch ----------------
extern "C" void kernel_launch(void* const* d_in, const int* in_sizes, int n_in,
                              void* d_out, int out_size, void* d_ws, size_t ws_size,
                              hipStream_t stream)
{
    const float* x    = (const float*)d_in[0];
    const float* ea   = (const float*)d_in[1];
    const int*   ei   = (const int*)d_in[2];
    const float* Win0 = (const float*)d_in[4];
    const float* bin0 = (const float*)d_in[5];
    const float* Win1 = (const float*)d_in[6];
    const float* bin1 = (const float*)d_in[7];
    const float* W1a  = (const float*)d_in[8];
    const float* b1a  = (const float*)d_in[9];
    const float* W1b  = (const float*)d_in[10];
    const float* b1b  = (const float*)d_in[11];
    const float* W2a  = (const float*)d_in[12];
    const float* b2a  = (const float*)d_in[13];
    const float* W2b  = (const float*)d_in[14];
    const float* b2b  = (const float*)d_in[15];
    const float* gmm  = (const float*)d_in[16];
    const float* bta  = (const float*)d_in[17];
    const float* Wf   = (const float*)d_in[18];
    const float* bfv  = (const float*)d_in[19];
    const float* Wo   = (const float*)d_in[20];
    const float* bo   = (const float*)d_in[21];
    float* out = (float*)d_out;

    float* ws   = (float*)d_ws;
    float* h    = ws;                          // NN*HD f32
    float* rbuf = h    + (size_t)NN*HD;        // NN*HD f32
    float* agg  = rbuf + (size_t)NN*HD;        // NN*HD f32
    float* rd   = agg  + (size_t)NN*HD;        // NN f32
    float* bn   = rd   + NN;                   // 256 f32
    int*   cnt  = (int*)(bn + 256);            // NN int   (cnt+fill contiguous for one zero pass)
    int*   fill = cnt + NN;                    // NN int
    int*   off  = fill + NN;                   // NN int
    int*   eidx = off + NN;                    // NE int
    int*   sdst = eidx + NE;                   // NE int

    const int* srcp = ei;
    const int* dstp = ei + NE;

    const int GN = (NN + TE - 1) / TE;     // 782
    const int GE = NE / TE;                // 12500
    const int G4 = (NN*HD/4 + 255) / 256;  // 6250

    // ---- CSR build (per call; ws/out re-poisoned between calls) ----
    zero_i_k<<<(2*NN+255)/256, 256, 0, stream>>>(cnt, 2*NN);   // cnt + fill
    count_k<<<(NE+255)/256, 256, 0, stream>>>(dstp, cnt);
    scan_k<<<1, 1024, 0, stream>>>(cnt, off);
    rdenom_k<<<(NN+255)/256, 256, 0, stream>>>(cnt, rd);
    fill_k<<<(NE+255)/256, 256, 0, stream>>>(dstp, off, fill, eidx, sdst);

    input_mlp_k<<<GN, BLK, 0, stream>>>(x, Win0, bin0, Win1, bin1, h);

    for (int l = 0; l < 3; ++l) {
        zero_agg_bn_k<<<G4, 256, 0, stream>>>((float4*)agg, NN*HD/4, bn);
        edge_kernel<<<GE, BLK, 0, stream>>>(h, ea, srcp, eidx, sdst,
            W1a + (size_t)l*(HD+2)*HD, b1a + l*HD,
            W1b + (size_t)l*HD*HD,     b1b + l*HD, agg);
        node_kernel<<<GN, BLK, 0, stream>>>(h, agg, rd,
            W2a + (size_t)l*2*HD*HD, b2a + l*HD,
            W2b + (size_t)l*HD*HD,   b2b + l*HD, rbuf);
        bn_stats_k<<<400, 256, 0, stream>>>(rbuf, bn);
        bn_norm_k<<<G4, 256, 0, stream>>>(rbuf, bn, gmm + l*HD, bta + l*HD, h);
    }

    final_kernel<<<GN, BLK, 0, stream>>>(h, Wf, bfv, Wo, bo, out);
}

// Round 4
// 4497.200 us; speedup vs baseline: 2.0865x; 1.0609x over previous
//
#include <hip/hip_runtime.h>
#include <hip/hip_bf16.h>

#define NN 50000
#define NE 800000
#define HD 128
#define EPSV 1e-5f
#define TE 64
#define BLK 256
#define SROW 68    // sT row stride (floats): 272B, float4-aligned
#define SMROW 132  // sM row stride (floats): 528B, float4-aligned

__device__ __forceinline__ float sigm(float x){ return 1.0f/(1.0f+__expf(-x)); }
__device__ __forceinline__ void atomAddF(float* p, float v){ unsafeAtomicAdd(p, v); }

// ---------------- small utility kernels ----------------
__global__ void zero_i_k(int* __restrict__ p, int n){
    int i = blockIdx.x*blockDim.x + threadIdx.x;
    if (i < n) p[i] = 0;
}

__global__ void zero_bn_k(float* __restrict__ bn){
    bn[threadIdx.x] = 0.0f;
}

__global__ void count_k(const int* __restrict__ dst, int* __restrict__ cnt){
    int e = blockIdx.x*blockDim.x + threadIdx.x;
    if (e < NE) atomicAdd(&cnt[dst[e]], 1);
}

__global__ void rdenom_k(const int* __restrict__ cnt, float* __restrict__ rd){
    int i = blockIdx.x*blockDim.x + threadIdx.x;
    if (i < NN) rd[i] = 1.0f / fmaxf((float)cnt[i], 1.0f);
}

// single-block exclusive scan over NN ints -> CSR offsets; off[NN] = NE
__global__ __launch_bounds__(1024) void scan_k(const int* __restrict__ cnt, int* __restrict__ off){
    __shared__ int s[1024];
    __shared__ int carryS;
    const int tid = threadIdx.x;
    if (tid == 0) carryS = 0;
    __syncthreads();
    const int NCH = (NN + 1023) / 1024;
    for (int ch = 0; ch < NCH; ++ch){
        const int i = ch*1024 + tid;
        const int v = (i < NN) ? cnt[i] : 0;
        s[tid] = v;
        __syncthreads();
        #pragma unroll
        for (int ofs = 1; ofs < 1024; ofs <<= 1){
            int t = (tid >= ofs) ? s[tid-ofs] : 0;
            __syncthreads();
            s[tid] += t;
            __syncthreads();
        }
        const int carry = carryS;
        if (i < NN) off[i] = carry + s[tid] - v;  // exclusive
        __syncthreads();
        if (tid == 1023) carryS = carry + s[1023];
        __syncthreads();
    }
    if (tid == 0) off[NN] = NE;
}

// bucket-fill: eidx[slot] = original edge id (slot order within a node arbitrary)
__global__ void fill_k(const int* __restrict__ dst, const int* __restrict__ off,
                       int* __restrict__ fill, int* __restrict__ eidx){
    int e = blockIdx.x*blockDim.x + threadIdx.x;
    if (e < NE){
        int d = dst[e];
        int pos = atomicAdd(&fill[d], 1);
        eidx[off[d] + pos] = e;
    }
}

// ---------------- shared matvec tile core ----------------
// sT(k,e) = smem[k*SROW + e]. Thread: 4 cols (eg*4..) x 8 out-channels (c0..c0+7).
__device__ __forceinline__ void mv_acc(const float* sT, int krows,
        const float* __restrict__ W, int c0, int eg, float acc[4][8])
{
    const float* Wp = W + c0;
    #pragma unroll 2
    for (int k=0; k<krows; ++k) {
        const float4 sv = *(const float4*)(sT + k*SROW + eg*4);
        const float4 wa = *(const float4*)(Wp + k*HD);
        const float4 wb = *(const float4*)(Wp + k*HD + 4);
        const float s[4] = {sv.x, sv.y, sv.z, sv.w};
        const float w[8] = {wa.x,wa.y,wa.z,wa.w, wb.x,wb.y,wb.z,wb.w};
        #pragma unroll
        for (int i=0;i<4;++i)
            #pragma unroll
            for (int j=0;j<8;++j)
                acc[i][j] = fmaf(s[i], w[j], acc[i][j]);
    }
}

// gather-transpose 64 rows (node ids in rowsLDS) of [*,128] f32 into sT rows 0..127
__device__ __forceinline__ void stage_rows(float* smem, const float* __restrict__ base,
                                           const int* rowsLDS, int tid)
{
    const int e_lo = tid>>3, kq = tid&7;
    #pragma unroll
    for (int half=0; half<2; ++half) {
        const int e = e_lo + 32*half;
        const int row = rowsLDS[e];
        const float* p = base + (size_t)row*HD + kq*4;
        #pragma unroll
        for (int q=0; q<4; ++q) {
            const float4 v = *(const float4*)(p + q*32);
            const int kb = 4*kq + 32*q;
            smem[(kb+0)*SROW + e] = v.x;
            smem[(kb+1)*SROW + e] = v.y;
            smem[(kb+2)*SROW + e] = v.z;
            smem[(kb+3)*SROW + e] = v.w;
        }
    }
}

// ---------------- input MLP: h = relu(relu(x@W0+b0)@W1+b1) ----------------
__global__ __launch_bounds__(BLK) void input_mlp_k(
    const float* __restrict__ x,
    const float* __restrict__ W0, const float* __restrict__ b0,
    const float* __restrict__ W1, const float* __restrict__ b1,
    float* __restrict__ h)
{
    __shared__ float smem[130*SROW];
    const int tid = threadIdx.x;
    const int n0 = blockIdx.x * TE;

    #pragma unroll
    for (int it=0; it<(HD*TE)/BLK; ++it) {
        int task = it*BLK + tid;
        int e = task & (TE-1);
        int c = task >> 6;
        int n = n0 + e; if (n >= NN) n = NN-1;
        float x0 = x[n*2+0], x1 = x[n*2+1];
        smem[c*SROW + e] = fmaxf(fmaf(x0, W0[c], fmaf(x1, W0[HD+c], b0[c])), 0.0f);
    }
    __syncthreads();

    const int cg = tid & 15, eg = tid >> 4, c0 = cg*8;
    float acc[4][8];
    #pragma unroll
    for (int j=0;j<8;++j){ float bv=b1[c0+j];
        #pragma unroll
        for (int i=0;i<4;++i) acc[i][j]=bv; }
    mv_acc(smem, HD, W1, c0, eg, acc);

    #pragma unroll
    for (int i=0;i<4;++i){
        int n = n0 + eg*4 + i;
        if (n < NN) {
            float4 r0, r1;
            r0.x=fmaxf(acc[i][0],0.f); r0.y=fmaxf(acc[i][1],0.f);
            r0.z=fmaxf(acc[i][2],0.f); r0.w=fmaxf(acc[i][3],0.f);
            r1.x=fmaxf(acc[i][4],0.f); r1.y=fmaxf(acc[i][5],0.f);
            r1.z=fmaxf(acc[i][6],0.f); r1.w=fmaxf(acc[i][7],0.f);
            *(float4*)&h[(size_t)n*HD + c0]     = r0;
            *(float4*)&h[(size_t)n*HD + c0 + 4] = r1;
        }
    }
}

// ===== fused edge-MLP + mean-aggregate + node-update kernel =====
// Block owns nodes [n0, n0+64); processes its contiguous dst-sorted slot range
// [off[n0], off[n0+64)) in 64-edge chunks; reduces messages into per-thread
// register accumulators (no atomics, no msg buffer); then runs the node MLP.
__global__ __launch_bounds__(BLK) void edge_node_kernel(
    const float* __restrict__ h, const float* __restrict__ ea,
    const int* __restrict__ src, const int* __restrict__ eidx,
    const int* __restrict__ off, const float* __restrict__ rd,
    const float* __restrict__ W1a, const float* __restrict__ b1a,
    const float* __restrict__ W1b, const float* __restrict__ b1b,
    const float* __restrict__ W2a, const float* __restrict__ b2a,
    const float* __restrict__ W2b, const float* __restrict__ b2b,
    float* __restrict__ rbuf)
{
    __shared__ float smem[130*SROW];   // sT view: [k][e] stride SROW; sM view: [s][c] stride SMROW (extent 8448 < 128*SROW)
    __shared__ int s_src[TE];
    const int tid = threadIdx.x;
    const int n0 = blockIdx.x * TE;
    const int cg = tid & 15, eg = tid >> 4, c0 = cg*8;

    // this thread's owned nodes: local eg*4 .. eg*4+3 ; slot ranges o[i]..o[i+1]
    int o[5];
    #pragma unroll
    for (int i=0;i<5;++i){
        int n = n0 + eg*4 + i; if (n > NN) n = NN;
        o[i] = off[n];
    }
    const int S0 = off[n0];
    const int nEnd = (n0 + TE < NN) ? (n0 + TE) : NN;
    const int S1 = off[nEnd];

    float nacc[4][8];
    #pragma unroll
    for (int i=0;i<4;++i)
        #pragma unroll
        for (int j=0;j<8;++j) nacc[i][j]=0.f;

    for (int cs = S0; cs < S1; cs += TE) {
        // A: chunk indices + edge_attr (rows 128/129 don't overlap sM extent)
        if (tid < TE) {
            int slot = cs + tid; if (slot >= NE) slot = NE-1;
            const int et = eidx[slot];
            s_src[tid] = src[et];
            const float2 a = *(const float2*)&ea[(size_t)et*2];
            smem[128*SROW + tid] = a.x;
            smem[129*SROW + tid] = a.y;
        }
        __syncthreads();
        // B: gather h[src] transposed into rows 0..127
        stage_rows(smem, h, s_src, tid);
        __syncthreads();

        // GEMM1: K=130
        float acc[4][8];
        #pragma unroll
        for (int j=0;j<8;++j){ const float bv=b1a[c0+j];
            #pragma unroll
            for (int i=0;i<4;++i) acc[i][j]=bv; }
        mv_acc(smem, HD+2, W1a, c0, eg, acc);
        __syncthreads();
        // m1 = relu(acc) -> sT rows 0..127
        #pragma unroll
        for (int j=0;j<8;++j){
            float4 m0;
            m0.x=fmaxf(acc[0][j],0.f); m0.y=fmaxf(acc[1][j],0.f);
            m0.z=fmaxf(acc[2][j],0.f); m0.w=fmaxf(acc[3][j],0.f);
            *(float4*)&smem[(c0+j)*SROW + eg*4] = m0;
        }
        __syncthreads();
        // GEMM2: K=128
        float acc2[4][8];
        #pragma unroll
        for (int j=0;j<8;++j){ const float bv=b1b[c0+j];
            #pragma unroll
            for (int i=0;i<4;++i) acc2[i][j]=bv; }
        mv_acc(smem, HD, W1b, c0, eg, acc2);
        __syncthreads();
        // messages -> sM[s][c] (row-major per slot)
        #pragma unroll
        for (int i=0;i<4;++i){
            float4 a0, a1;
            a0.x=fmaxf(acc2[i][0],0.f); a0.y=fmaxf(acc2[i][1],0.f);
            a0.z=fmaxf(acc2[i][2],0.f); a0.w=fmaxf(acc2[i][3],0.f);
            a1.x=fmaxf(acc2[i][4],0.f); a1.y=fmaxf(acc2[i][5],0.f);
            a1.z=fmaxf(acc2[i][6],0.f); a1.w=fmaxf(acc2[i][7],0.f);
            float* mp = &smem[(eg*4+i)*SMROW + c0];
            *(float4*)mp = a0;
            *(float4*)(mp+4) = a1;
        }
        __syncthreads();
        // segment-reduce this thread's owned nodes' slots (off-ranges exclude tail garbage)
        #pragma unroll
        for (int i=0;i<4;++i){
            int lo = o[i]   > cs      ? o[i]   : cs;
            int hi = o[i+1] < cs + TE ? o[i+1] : cs + TE;
            for (int s = lo; s < hi; ++s){
                const float* mp = &smem[(s-cs)*SMROW + c0];
                const float4 a0 = *(const float4*)mp;
                const float4 a1 = *(const float4*)(mp+4);
                nacc[i][0]+=a0.x; nacc[i][1]+=a0.y; nacc[i][2]+=a0.z; nacc[i][3]+=a0.w;
                nacc[i][4]+=a1.x; nacc[i][5]+=a1.y; nacc[i][6]+=a1.z; nacc[i][7]+=a1.w;
            }
        }
        // no trailing barrier needed: next A writes only rows 128/129 + s_src
        // (disjoint from sM), and the post-A barrier orders staging vs reduce.
    }

    // ---- node update phase: u = relu(W2a·[h; nacc*rd]+b2a); r = h + sigm(W2b·u+b2b)
    #pragma unroll
    for (int i=0;i<4;++i){
        const int n = n0 + eg*4 + i;
        const float rdv = (n < NN) ? rd[n] : 0.f;
        #pragma unroll
        for (int j=0;j<8;++j) nacc[i][j] *= rdv;
    }
    __syncthreads();   // all chunk reduces done before restaging smem
    if (tid < TE) { int n = n0 + tid; s_src[tid] = (n < NN) ? n : NN-1; }
    __syncthreads();
    stage_rows(smem, h, s_src, tid);
    __syncthreads();

    float acc[4][8];
    #pragma unroll
    for (int j=0;j<8;++j){ const float bv=b2a[c0+j];
        #pragma unroll
        for (int i=0;i<4;++i) acc[i][j]=bv; }
    mv_acc(smem, HD, W2a, c0, eg, acc);      // K-half 1: h
    __syncthreads();
    // write nacc (already mean-scaled) transposed into rows 0..127
    #pragma unroll
    for (int j=0;j<8;++j){
        float4 m0 = make_float4(nacc[0][j], nacc[1][j], nacc[2][j], nacc[3][j]);
        *(float4*)&smem[(c0+j)*SROW + eg*4] = m0;
    }
    __syncthreads();
    mv_acc(smem, HD, W2a + HD*HD, c0, eg, acc);  // K-half 2: agg
    __syncthreads();
    // u = relu(acc) -> rows 0..127
    #pragma unroll
    for (int j=0;j<8;++j){
        float4 m0;
        m0.x=fmaxf(acc[0][j],0.f); m0.y=fmaxf(acc[1][j],0.f);
        m0.z=fmaxf(acc[2][j],0.f); m0.w=fmaxf(acc[3][j],0.f);
        *(float4*)&smem[(c0+j)*SROW + eg*4] = m0;
    }
    __syncthreads();
    float acc2[4][8];
    #pragma unroll
    for (int j=0;j<8;++j){ const float bv=b2b[c0+j];
        #pragma unroll
        for (int i=0;i<4;++i) acc2[i][j]=bv; }
    mv_acc(smem, HD, W2b, c0, eg, acc2);

    #pragma unroll
    for (int i=0;i<4;++i){
        const int n = n0 + eg*4 + i;
        if (n < NN) {
            const float4 h0 = *(const float4*)&h[(size_t)n*HD + c0];
            const float4 h1 = *(const float4*)&h[(size_t)n*HD + c0 + 4];
            float4 r0, r1;
            r0.x = h0.x + sigm(acc2[i][0]); r0.y = h0.y + sigm(acc2[i][1]);
            r0.z = h0.z + sigm(acc2[i][2]); r0.w = h0.w + sigm(acc2[i][3]);
            r1.x = h1.x + sigm(acc2[i][4]); r1.y = h1.y + sigm(acc2[i][5]);
            r1.z = h1.z + sigm(acc2[i][6]); r1.w = h1.w + sigm(acc2[i][7]);
            *(float4*)&rbuf[(size_t)n*HD + c0]     = r0;
            *(float4*)&rbuf[(size_t)n*HD + c0 + 4] = r1;
        }
    }
}

// ---------------- BN stats: bn[c]=sum, bn[128+c]=sumsq ----------------
__global__ void bn_stats_k(const float* __restrict__ r, float* __restrict__ bn){
    const int c = threadIdx.x & (HD-1);
    const int half = threadIdx.x >> 7;
    const int stride = gridDim.x * 2;
    float s = 0.f, ss = 0.f;
    for (int n = blockIdx.x*2 + half; n < NN; n += stride) {
        const float v = r[(size_t)n*HD + c];
        s += v; ss += v*v;
    }
    atomAddF(&bn[c], s);
    atomAddF(&bn[HD+c], ss);
}

// ---------------- BN normalize ----------------
__global__ void bn_norm_k(const float* __restrict__ r, const float* __restrict__ bn,
                          const float* __restrict__ gamma, const float* __restrict__ beta,
                          float* __restrict__ h){
    const int i = blockIdx.x*blockDim.x + threadIdx.x;  // float4 index
    const int n4 = NN*HD/4;
    if (i >= n4) return;
    const int c0 = (i*4) & (HD-1);
    float4 v = ((const float4*)r)[i];
    float* vp = (float*)&v;
    #pragma unroll
    for (int j=0;j<4;++j){
        const int c = c0 + j;
        const float mu  = bn[c] * (1.0f/NN);
        const float var = bn[HD+c] * (1.0f/NN) - mu*mu;
        const float sc  = rsqrtf(var + EPSV) * gamma[c];
        const float sh  = beta[c] - mu*sc;
        vp[j] = fmaf(vp[j], sc, sh);
    }
    ((float4*)h)[i] = v;
}

// ---------------- final MLP ----------------
__global__ __launch_bounds__(BLK) void final_kernel(
    const float* __restrict__ h,
    const float* __restrict__ Wf, const float* __restrict__ bf,
    const float* __restrict__ Wo, const float* __restrict__ bo,
    float* __restrict__ out)
{
    __shared__ float smem[130*SROW];
    __shared__ int s_src[TE];
    const int tid = threadIdx.x;
    const int n0 = blockIdx.x * TE;
    const int cg = tid & 15, eg = tid >> 4, c0 = cg*8;

    if (tid < TE) { int n = n0 + tid; s_src[tid] = (n < NN) ? n : NN-1; }
    __syncthreads();
    stage_rows(smem, h, s_src, tid);
    __syncthreads();

    float acc[4][8];
    #pragma unroll
    for (int j=0;j<8;++j){ float bv=bf[c0+j];
        #pragma unroll
        for (int i=0;i<4;++i) acc[i][j]=bv; }
    mv_acc(smem, HD, Wf, c0, eg, acc);
    __syncthreads();

    #pragma unroll
    for (int j=0;j<8;++j){
        float4 m0;
        m0.x=fmaxf(acc[0][j],0.f); m0.y=fmaxf(acc[1][j],0.f);
        m0.z=fmaxf(acc[2][j],0.f); m0.w=fmaxf(acc[3][j],0.f);
        *(float4*)&smem[(c0+j)*SROW + eg*4] = m0;
    }
    __syncthreads();

    const int e = tid >> 2, q = tid & 3;
    float s = 0.f;
    #pragma unroll
    for (int kk=0; kk<32; ++kk) {
        const int k = q*32 + kk;
        s = fmaf(smem[k*SROW + e], Wo[k], s);
    }
    s += __shfl_xor(s, 1);
    s += __shfl_xor(s, 2);
    const int n = n0 + e;
    if (q == 0 && n < NN)
        out[n] = sigm(s + bo[0]);
}

// ---------------- launch ----------------
extern "C" void kernel_launch(void* const* d_in, const int* in_sizes, int n_in,
                              void* d_out, int out_size, void* d_ws, size_t ws_size,
                              hipStream_t stream)
{
    const float* x    = (const float*)d_in[0];
    const float* ea   = (const float*)d_in[1];
    const int*   ei   = (const int*)d_in[2];
    const float* Win0 = (const float*)d_in[4];
    const float* bin0 = (const float*)d_in[5];
    const float* Win1 = (const float*)d_in[6];
    const float* bin1 = (const float*)d_in[7];
    const float* W1a  = (const float*)d_in[8];
    const float* b1a  = (const float*)d_in[9];
    const float* W1b  = (const float*)d_in[10];
    const float* b1b  = (const float*)d_in[11];
    const float* W2a  = (const float*)d_in[12];
    const float* b2a  = (const float*)d_in[13];
    const float* W2b  = (const float*)d_in[14];
    const float* b2b  = (const float*)d_in[15];
    const float* gmm  = (const float*)d_in[16];
    const float* bta  = (const float*)d_in[17];
    const float* Wf   = (const float*)d_in[18];
    const float* bfv  = (const float*)d_in[19];
    const float* Wo   = (const float*)d_in[20];
    const float* bo   = (const float*)d_in[21];
    float* out = (float*)d_out;

    float* ws   = (float*)d_ws;
    float* h    = ws;                          // NN*HD f32
    float* rbuf = h    + (size_t)NN*HD;        // NN*HD f32
    float* rd   = rbuf + (size_t)NN*HD;        // NN f32
    float* bn   = rd   + NN;                   // 256 f32
    int*   cnt  = (int*)(bn + 256);            // NN int (cnt+fill contiguous zero)
    int*   fill = cnt + NN;                    // NN int
    int*   off  = fill + NN;                   // NN+1 int
    int*   eidx = off + NN + 1;                // NE int

    const int* srcp = ei;
    const int* dstp = ei + NE;

    const int GN = (NN + TE - 1) / TE;     // 782
    const int G4 = (NN*HD/4 + 255) / 256;  // 6250

    // ---- CSR build ----
    zero_i_k<<<(2*NN+255)/256, 256, 0, stream>>>(cnt, 2*NN);
    count_k<<<(NE+255)/256, 256, 0, stream>>>(dstp, cnt);
    scan_k<<<1, 1024, 0, stream>>>(cnt, off);
    rdenom_k<<<(NN+255)/256, 256, 0, stream>>>(cnt, rd);
    fill_k<<<(NE+255)/256, 256, 0, stream>>>(dstp, off, fill, eidx);

    input_mlp_k<<<GN, BLK, 0, stream>>>(x, Win0, bin0, Win1, bin1, h);

    for (int l = 0; l < 3; ++l) {
        zero_bn_k<<<1, 256, 0, stream>>>(bn);
        edge_node_kernel<<<GN, BLK, 0, stream>>>(h, ea, srcp, eidx, off, rd,
            W1a + (size_t)l*(HD+2)*HD, b1a + l*HD,
            W1b + (size_t)l*HD*HD,     b1b + l*HD,
            W2a + (size_t)l*2*HD*HD,   b2a + l*HD,
            W2b + (size_t)l*HD*HD,     b2b + l*HD, rbuf);
        bn_stats_k<<<400, 256, 0, stream>>>(rbuf, bn);
        bn_norm_k<<<G4, 256, 0, stream>>>(rbuf, bn, gmm + l*HD, bta + l*HD, h);
    }

    final_kernel<<<GN, BLK, 0, stream>>>(h, Wf, bfv, Wo, bo, out);
}

// Round 5
// 1422.734 us; speedup vs baseline: 6.5953x; 3.1610x over previous
//
#include <hip/hip_runtime.h>
#include <hip/hip_bf16.h>

#define NN 50000
#define NE 800000
#define HD 128
#define EPSV 1e-5f
#define TE 64
#define BLK 256
#define SROW 68          // fp32 LDS row stride for input/final kernels
#define ASTR 336         // bufA row stride bytes: 168 bf16 (84 dw -> conflict-free)
#define BSTR 272         // bufB row stride bytes: 136 bf16 (68 dw -> conflict-free)

typedef unsigned short u16;
typedef __attribute__((ext_vector_type(8))) short bf16x8;
typedef __attribute__((ext_vector_type(4))) float f32x4;
#define MFMA16 __builtin_amdgcn_mfma_f32_16x16x32_bf16

__device__ __forceinline__ float sigm(float x){ return 1.0f/(1.0f+__expf(-x)); }
__device__ __forceinline__ void atomAddF(float* p, float v){ unsafeAtomicAdd(p, v); }
__device__ __forceinline__ unsigned bfr(float x){           // f32 -> bf16 bits (RNE)
    unsigned u = __float_as_uint(x);
    return (u + 0x7FFFu + ((u>>16)&1u)) >> 16;
}
__device__ __forceinline__ float bf2f(unsigned u){ return __uint_as_float(u<<16); }

// ---------------- small utility kernels ----------------
__global__ void zero_i_k(int* __restrict__ p, int n){
    int i = blockIdx.x*blockDim.x + threadIdx.x;
    if (i < n) p[i] = 0;
}
__global__ void zero_bn_k(float* __restrict__ bn){ bn[threadIdx.x] = 0.0f; }

__global__ void count_k(const int* __restrict__ dst, int* __restrict__ cnt){
    int e = blockIdx.x*blockDim.x + threadIdx.x;
    if (e < NE) atomicAdd(&cnt[dst[e]], 1);
}
__global__ void rdenom_k(const int* __restrict__ cnt, float* __restrict__ rd){
    int i = blockIdx.x*blockDim.x + threadIdx.x;
    if (i < NN) rd[i] = 1.0f / fmaxf((float)cnt[i], 1.0f);
}

// single-block exclusive scan over NN ints -> CSR offsets; off[NN] = NE
__global__ __launch_bounds__(1024) void scan_k(const int* __restrict__ cnt, int* __restrict__ off){
    __shared__ int s[1024];
    __shared__ int carryS;
    const int tid = threadIdx.x;
    if (tid == 0) carryS = 0;
    __syncthreads();
    const int NCH = (NN + 1023) / 1024;
    for (int ch = 0; ch < NCH; ++ch){
        const int i = ch*1024 + tid;
        const int v = (i < NN) ? cnt[i] : 0;
        s[tid] = v;
        __syncthreads();
        #pragma unroll
        for (int ofs = 1; ofs < 1024; ofs <<= 1){
            int t = (tid >= ofs) ? s[tid-ofs] : 0;
            __syncthreads();
            s[tid] += t;
            __syncthreads();
        }
        const int carry = carryS;
        if (i < NN) off[i] = carry + s[tid] - v;
        __syncthreads();
        if (tid == 1023) carryS = carry + s[1023];
        __syncthreads();
    }
    if (tid == 0) off[NN] = NE;
}

__global__ void fill_k(const int* __restrict__ dst, const int* __restrict__ off,
                       int* __restrict__ fill, int* __restrict__ eidx){
    int e = blockIdx.x*blockDim.x + threadIdx.x;
    if (e < NE){
        int d = dst[e];
        int pos = atomicAdd(&fill[d], 1);
        eidx[off[d] + pos] = e;
    }
}

// weight convert+transpose: src f32 [K][H] -> dst bf16 [H][KP], zero-padded K..KP
__global__ void wconv_k(const float* __restrict__ src, u16* __restrict__ dst,
                        int K, int KP, int H){
    int idx = blockIdx.x*blockDim.x + threadIdx.x;
    if (idx >= H*KP) return;
    int c = idx / KP, k = idx - c*KP;
    dst[idx] = (k < K) ? (u16)bfr(src[k*H + c]) : (u16)0;
}

// ---------------- fp32 matvec core (input/final kernels only) ----------------
__device__ __forceinline__ void mv_acc(const float* sT, int krows,
        const float* __restrict__ W, int c0, int eg, float acc[4][8])
{
    const float* Wp = W + c0;
    #pragma unroll 2
    for (int k=0; k<krows; ++k) {
        const float4 sv = *(const float4*)(sT + k*SROW + eg*4);
        const float4 wa = *(const float4*)(Wp + k*HD);
        const float4 wb = *(const float4*)(Wp + k*HD + 4);
        const float s[4] = {sv.x, sv.y, sv.z, sv.w};
        const float w[8] = {wa.x,wa.y,wa.z,wa.w, wb.x,wb.y,wb.z,wb.w};
        #pragma unroll
        for (int i=0;i<4;++i)
            #pragma unroll
            for (int j=0;j<8;++j)
                acc[i][j] = fmaf(s[i], w[j], acc[i][j]);
    }
}

__device__ __forceinline__ void stage_rows(float* smem, const float* __restrict__ base,
                                           const int* rowsLDS, int tid)
{
    const int e_lo = tid>>3, kq = tid&7;
    #pragma unroll
    for (int half=0; half<2; ++half) {
        const int e = e_lo + 32*half;
        const int row = rowsLDS[e];
        const float* p = base + (size_t)row*HD + kq*4;
        #pragma unroll
        for (int q=0; q<4; ++q) {
            const float4 v = *(const float4*)(p + q*32);
            const int kb = 4*kq + 32*q;
            smem[(kb+0)*SROW + e] = v.x;
            smem[(kb+1)*SROW + e] = v.y;
            smem[(kb+2)*SROW + e] = v.z;
            smem[(kb+3)*SROW + e] = v.w;
        }
    }
}

// ---------------- input MLP: h = relu(relu(x@W0+b0)@W1+b1); also bf16 mirror ----
__global__ __launch_bounds__(BLK) void input_mlp_k(
    const float* __restrict__ x,
    const float* __restrict__ W0, const float* __restrict__ b0,
    const float* __restrict__ W1, const float* __restrict__ b1,
    float* __restrict__ h, u16* __restrict__ hb)
{
    __shared__ float smem[130*SROW];
    const int tid = threadIdx.x;
    const int n0 = blockIdx.x * TE;

    #pragma unroll
    for (int it=0; it<(HD*TE)/BLK; ++it) {
        int task = it*BLK + tid;
        int e = task & (TE-1);
        int c = task >> 6;
        int n = n0 + e; if (n >= NN) n = NN-1;
        float x0 = x[n*2+0], x1 = x[n*2+1];
        smem[c*SROW + e] = fmaxf(fmaf(x0, W0[c], fmaf(x1, W0[HD+c], b0[c])), 0.0f);
    }
    __syncthreads();

    const int cg = tid & 15, eg = tid >> 4, c0 = cg*8;
    float acc[4][8];
    #pragma unroll
    for (int j=0;j<8;++j){ float bv=b1[c0+j];
        #pragma unroll
        for (int i=0;i<4;++i) acc[i][j]=bv; }
    mv_acc(smem, HD, W1, c0, eg, acc);

    #pragma unroll
    for (int i=0;i<4;++i){
        int n = n0 + eg*4 + i;
        if (n < NN) {
            float4 r0, r1;
            r0.x=fmaxf(acc[i][0],0.f); r0.y=fmaxf(acc[i][1],0.f);
            r0.z=fmaxf(acc[i][2],0.f); r0.w=fmaxf(acc[i][3],0.f);
            r1.x=fmaxf(acc[i][4],0.f); r1.y=fmaxf(acc[i][5],0.f);
            r1.z=fmaxf(acc[i][6],0.f); r1.w=fmaxf(acc[i][7],0.f);
            *(float4*)&h[(size_t)n*HD + c0]     = r0;
            *(float4*)&h[(size_t)n*HD + c0 + 4] = r1;
            uint4 pk;
            pk.x = bfr(r0.x)|(bfr(r0.y)<<16); pk.y = bfr(r0.z)|(bfr(r0.w)<<16);
            pk.z = bfr(r1.x)|(bfr(r1.y)<<16); pk.w = bfr(r1.z)|(bfr(r1.w)<<16);
            *(uint4*)&hb[(size_t)n*HD + c0] = pk;
        }
    }
}

// ===== MFMA fused edge-MLP + mean-aggregate + node-update =====
// Weights = A operand (row=channel, k contiguous from WT[c][k]);
// features = B operand (col=edge/node, k contiguous from row-major LDS tiles);
// D (col=e, row=c) -> ds_write_b64 packs into next tile's [e][c] layout.
__global__ __launch_bounds__(BLK, 4) void edge_node_kernel(
    const float* __restrict__ h, const u16* __restrict__ hb,
    const float* __restrict__ ea,
    const int* __restrict__ src, const int* __restrict__ eidx,
    const int* __restrict__ off, const float* __restrict__ rd,
    const u16* __restrict__ W1aT, const float* __restrict__ b1a,
    const u16* __restrict__ W1bT, const float* __restrict__ b1b,
    const u16* __restrict__ W2aT, const float* __restrict__ b2a,
    const u16* __restrict__ W2bT, const float* __restrict__ b2b,
    float* __restrict__ rbuf)
{
    __shared__ char bufA[TE*ASTR];   // feature tile [64][168] bf16 (K up to 160 used)
    __shared__ char bufB[TE*BSTR];   // m1 / m2 / u tile [64][136] bf16
    __shared__ int s_src[TE], s_et[TE];

    const int tid = threadIdx.x;
    const int lane = tid & 63;
    const int l15 = lane & 15, lhi = lane >> 4;     // D: col=l15, row=lhi*4+reg
    const int w = tid >> 6;                          // wave 0..3 -> c-tiles 2w,2w+1
    const int n0 = blockIdx.x * TE;
    const int cg = tid & 15, eg = tid >> 4, c0 = cg*8;   // reduce mapping

    // zero bufA row tails [256,336) once (GEMM1 pad k in [130,160))
    for (int idx = tid; idx < TE*5; idx += BLK){
        const int r = idx/5, q = idx - r*5;
        *(uint4*)(bufA + r*ASTR + 256 + q*16) = make_uint4(0u,0u,0u,0u);
    }

    int o[5];
    #pragma unroll
    for (int i=0;i<5;++i){
        int n = n0 + eg*4 + i; if (n > NN) n = NN;
        o[i] = off[n];
    }
    const int S0 = off[n0];
    const int nEnd = (n0 + TE < NN) ? (n0 + TE) : NN;
    const int S1 = off[nEnd];

    float nacc[4][8];
    #pragma unroll
    for (int i=0;i<4;++i)
        #pragma unroll
        for (int j=0;j<8;++j) nacc[i][j]=0.f;

    __syncthreads();

    for (int cs = S0; cs < S1; cs += TE) {
        if (tid < TE) {
            int slot = cs + tid; if (slot > NE-1) slot = NE-1;
            const int et = eidx[slot];
            s_et[tid] = et;
            s_src[tid] = src[et];
        }
        __syncthreads();                               // bar1: s_src/s_et ready
        {   // stage hb[src] rows (256B each) + edge_attr at bytes [256,260)
            const int r = tid>>2, p = tid&3;
            const uint4* sp = (const uint4*)(hb + (size_t)s_src[r]*HD);
            uint4* dp = (uint4*)(bufA + r*ASTR + p*64);
            #pragma unroll
            for (int q=0;q<4;++q) dp[q] = sp[p*4+q];
            if (p == 0){
                const float2 a = *(const float2*)&ea[(size_t)s_et[r]*2];
                *(unsigned*)(bufA + r*ASTR + 256) = bfr(a.x) | (bfr(a.y)<<16);
            }
        }
        __syncthreads();                               // bar2: tile staged

        // ---- GEMM1: m1[c][e] = W1a^T(160k) x feat ----
        f32x4 acc1[2][4];
        #pragma unroll
        for (int cc=0; cc<2; ++cc){
            const float4 bv = *(const float4*)&b1a[(2*w+cc)*16 + lhi*4];
            #pragma unroll
            for (int te=0; te<4; ++te){
                acc1[cc][te][0]=bv.x; acc1[cc][te][1]=bv.y;
                acc1[cc][te][2]=bv.z; acc1[cc][te][3]=bv.w;
            }
        }
        #pragma unroll
        for (int kk=0; kk<5; ++kk){
            const bf16x8 a0 = *(const bf16x8*)(W1aT + ((2*w  )*16 + l15)*160 + kk*32 + lhi*8);
            const bf16x8 a1 = *(const bf16x8*)(W1aT + ((2*w+1)*16 + l15)*160 + kk*32 + lhi*8);
            #pragma unroll
            for (int te=0; te<4; ++te){
                const bf16x8 bb = *(const bf16x8*)(bufA + (te*16+l15)*ASTR + kk*64 + lhi*16);
                acc1[0][te] = MFMA16(a0, bb, acc1[0][te], 0,0,0);
                acc1[1][te] = MFMA16(a1, bb, acc1[1][te], 0,0,0);
            }
        }
        #pragma unroll
        for (int cc=0; cc<2; ++cc){
            #pragma unroll
            for (int te=0; te<4; ++te){
                uint2 pk;
                pk.x = bfr(fmaxf(acc1[cc][te][0],0.f)) | (bfr(fmaxf(acc1[cc][te][1],0.f))<<16);
                pk.y = bfr(fmaxf(acc1[cc][te][2],0.f)) | (bfr(fmaxf(acc1[cc][te][3],0.f))<<16);
                *(uint2*)(bufB + (te*16+l15)*BSTR + (2*w+cc)*32 + lhi*8) = pk;
            }
        }
        __syncthreads();                               // bar3: m1 ready

        // ---- GEMM2: m2[c][e] = W1b^T(128k) x m1 ----
        f32x4 acc2[2][4];
        #pragma unroll
        for (int cc=0; cc<2; ++cc){
            const float4 bv = *(const float4*)&b1b[(2*w+cc)*16 + lhi*4];
            #pragma unroll
            for (int te=0; te<4; ++te){
                acc2[cc][te][0]=bv.x; acc2[cc][te][1]=bv.y;
                acc2[cc][te][2]=bv.z; acc2[cc][te][3]=bv.w;
            }
        }
        #pragma unroll
        for (int kk=0; kk<4; ++kk){
            const bf16x8 a0 = *(const bf16x8*)(W1bT + ((2*w  )*16 + l15)*128 + kk*32 + lhi*8);
            const bf16x8 a1 = *(const bf16x8*)(W1bT + ((2*w+1)*16 + l15)*128 + kk*32 + lhi*8);
            #pragma unroll
            for (int te=0; te<4; ++te){
                const bf16x8 bb = *(const bf16x8*)(bufB + (te*16+l15)*BSTR + kk*64 + lhi*16);
                acc2[0][te] = MFMA16(a0, bb, acc2[0][te], 0,0,0);
                acc2[1][te] = MFMA16(a1, bb, acc2[1][te], 0,0,0);
            }
        }
        __syncthreads();                               // bar4: m1 reads done
        #pragma unroll
        for (int cc=0; cc<2; ++cc){
            #pragma unroll
            for (int te=0; te<4; ++te){
                uint2 pk;
                pk.x = bfr(fmaxf(acc2[cc][te][0],0.f)) | (bfr(fmaxf(acc2[cc][te][1],0.f))<<16);
                pk.y = bfr(fmaxf(acc2[cc][te][2],0.f)) | (bfr(fmaxf(acc2[cc][te][3],0.f))<<16);
                *(uint2*)(bufB + (te*16+l15)*BSTR + (2*w+cc)*32 + lhi*8) = pk;
            }
        }
        __syncthreads();                               // bar5: m2 ready

        // segment-reduce owned nodes' slots into registers
        #pragma unroll
        for (int i=0;i<4;++i){
            int lo = o[i]   > cs      ? o[i]   : cs;
            int hi = o[i+1] < cs + TE ? o[i+1] : cs + TE;
            for (int s = lo; s < hi; ++s){
                const uint4 v = *(const uint4*)(bufB + (s-cs)*BSTR + cg*16);
                nacc[i][0] += bf2f(v.x&0xffffu); nacc[i][1] += bf2f(v.x>>16);
                nacc[i][2] += bf2f(v.y&0xffffu); nacc[i][3] += bf2f(v.y>>16);
                nacc[i][4] += bf2f(v.z&0xffffu); nacc[i][5] += bf2f(v.z>>16);
                nacc[i][6] += bf2f(v.w&0xffffu); nacc[i][7] += bf2f(v.w>>16);
            }
        }
    }

    // ---- node update: u = relu(W2a^T.[h;agg]); r = h + sigm(W2b^T.u) ----
    #pragma unroll
    for (int i=0;i<4;++i){
        const int n = n0 + eg*4 + i;
        const float rdv = (n < NN) ? rd[n] : 0.f;
        #pragma unroll
        for (int j=0;j<8;++j) nacc[i][j] *= rdv;
    }
    __syncthreads();                                   // chunk loop fully drained
    {   // stage hb rows n0..n0+63
        const int r = tid>>2, p = tid&3;
        int n = n0 + r; if (n >= NN) n = NN-1;
        const uint4* sp = (const uint4*)(hb + (size_t)n*HD);
        uint4* dp = (uint4*)(bufA + r*ASTR + p*64);
        #pragma unroll
        for (int q=0;q<4;++q) dp[q] = sp[p*4+q];
    }
    __syncthreads();

    f32x4 accN[2][4];
    #pragma unroll
    for (int cc=0; cc<2; ++cc){
        const float4 bv = *(const float4*)&b2a[(2*w+cc)*16 + lhi*4];
        #pragma unroll
        for (int te=0; te<4; ++te){
            accN[cc][te][0]=bv.x; accN[cc][te][1]=bv.y;
            accN[cc][te][2]=bv.z; accN[cc][te][3]=bv.w;
        }
    }
    #pragma unroll
    for (int kk=0; kk<4; ++kk){                         // K-half 1: h
        const bf16x8 a0 = *(const bf16x8*)(W2aT + ((2*w  )*16 + l15)*256 + kk*32 + lhi*8);
        const bf16x8 a1 = *(const bf16x8*)(W2aT + ((2*w+1)*16 + l15)*256 + kk*32 + lhi*8);
        #pragma unroll
        for (int te=0; te<4; ++te){
            const bf16x8 bb = *(const bf16x8*)(bufA + (te*16+l15)*ASTR + kk*64 + lhi*16);
            accN[0][te] = MFMA16(a0, bb, accN[0][te], 0,0,0);
            accN[1][te] = MFMA16(a1, bb, accN[1][te], 0,0,0);
        }
    }
    __syncthreads();
    #pragma unroll
    for (int i=0;i<4;++i){                              // stage agg (bf16) over h tile
        uint4 pk;
        pk.x = bfr(nacc[i][0]) | (bfr(nacc[i][1])<<16);
        pk.y = bfr(nacc[i][2]) | (bfr(nacc[i][3])<<16);
        pk.z = bfr(nacc[i][4]) | (bfr(nacc[i][5])<<16);
        pk.w = bfr(nacc[i][6]) | (bfr(nacc[i][7])<<16);
        *(uint4*)(bufA + (eg*4+i)*ASTR + cg*16) = pk;
    }
    __syncthreads();
    #pragma unroll
    for (int kk=0; kk<4; ++kk){                         // K-half 2: agg
        const bf16x8 a0 = *(const bf16x8*)(W2aT + ((2*w  )*16 + l15)*256 + 128 + kk*32 + lhi*8);
        const bf16x8 a1 = *(const bf16x8*)(W2aT + ((2*w+1)*16 + l15)*256 + 128 + kk*32 + lhi*8);
        #pragma unroll
        for (int te=0; te<4; ++te){
            const bf16x8 bb = *(const bf16x8*)(bufA + (te*16+l15)*ASTR + kk*64 + lhi*16);
            accN[0][te] = MFMA16(a0, bb, accN[0][te], 0,0,0);
            accN[1][te] = MFMA16(a1, bb, accN[1][te], 0,0,0);
        }
    }
    #pragma unroll
    for (int cc=0; cc<2; ++cc){                         // u = relu -> bufB
        #pragma unroll
        for (int te=0; te<4; ++te){
            uint2 pk;
            pk.x = bfr(fmaxf(accN[cc][te][0],0.f)) | (bfr(fmaxf(accN[cc][te][1],0.f))<<16);
            pk.y = bfr(fmaxf(accN[cc][te][2],0.f)) | (bfr(fmaxf(accN[cc][te][3],0.f))<<16);
            *(uint2*)(bufB + (te*16+l15)*BSTR + (2*w+cc)*32 + lhi*8) = pk;
        }
    }
    __syncthreads();

    f32x4 accO[2][4];
    #pragma unroll
    for (int cc=0; cc<2; ++cc){
        const float4 bv = *(const float4*)&b2b[(2*w+cc)*16 + lhi*4];
        #pragma unroll
        for (int te=0; te<4; ++te){
            accO[cc][te][0]=bv.x; accO[cc][te][1]=bv.y;
            accO[cc][te][2]=bv.z; accO[cc][te][3]=bv.w;
        }
    }
    #pragma unroll
    for (int kk=0; kk<4; ++kk){
        const bf16x8 a0 = *(const bf16x8*)(W2bT + ((2*w  )*16 + l15)*128 + kk*32 + lhi*8);
        const bf16x8 a1 = *(const bf16x8*)(W2bT + ((2*w+1)*16 + l15)*128 + kk*32 + lhi*8);
        #pragma unroll
        for (int te=0; te<4; ++te){
            const bf16x8 bb = *(const bf16x8*)(bufB + (te*16+l15)*BSTR + kk*64 + lhi*16);
            accO[0][te] = MFMA16(a0, bb, accO[0][te], 0,0,0);
            accO[1][te] = MFMA16(a1, bb, accO[1][te], 0,0,0);
        }
    }
    #pragma unroll
    for (int cc=0; cc<2; ++cc){
        const int cbase = (2*w+cc)*16 + lhi*4;
        #pragma unroll
        for (int te=0; te<4; ++te){
            const int n = n0 + te*16 + l15;
            if (n < NN){
                const float4 hv = *(const float4*)&h[(size_t)n*HD + cbase];
                float4 r;
                r.x = hv.x + sigm(accO[cc][te][0]);
                r.y = hv.y + sigm(accO[cc][te][1]);
                r.z = hv.z + sigm(accO[cc][te][2]);
                r.w = hv.w + sigm(accO[cc][te][3]);
                *(float4*)&rbuf[(size_t)n*HD + cbase] = r;
            }
        }
    }
}

// ---------------- BN stats ----------------
__global__ void bn_stats_k(const float* __restrict__ r, float* __restrict__ bn){
    const int c = threadIdx.x & (HD-1);
    const int half = threadIdx.x >> 7;
    const int stride = gridDim.x * 2;
    float s = 0.f, ss = 0.f;
    for (int n = blockIdx.x*2 + half; n < NN; n += stride) {
        const float v = r[(size_t)n*HD + c];
        s += v; ss += v*v;
    }
    atomAddF(&bn[c], s);
    atomAddF(&bn[HD+c], ss);
}

// ---------------- BN normalize (writes f32 h + bf16 mirror) ----------------
__global__ void bn_norm_k(const float* __restrict__ r, const float* __restrict__ bn,
                          const float* __restrict__ gamma, const float* __restrict__ beta,
                          float* __restrict__ h, u16* __restrict__ hb){
    const int i = blockIdx.x*blockDim.x + threadIdx.x;  // float4 index
    const int n4 = NN*HD/4;
    if (i >= n4) return;
    const int c0 = (i*4) & (HD-1);
    float4 v = ((const float4*)r)[i];
    float* vp = (float*)&v;
    #pragma unroll
    for (int j=0;j<4;++j){
        const int c = c0 + j;
        const float mu  = bn[c] * (1.0f/NN);
        const float var = bn[HD+c] * (1.0f/NN) - mu*mu;
        const float sc  = rsqrtf(var + EPSV) * gamma[c];
        const float sh  = beta[c] - mu*sc;
        vp[j] = fmaf(vp[j], sc, sh);
    }
    ((float4*)h)[i] = v;
    uint2 pk;
    pk.x = bfr(vp[0]) | (bfr(vp[1])<<16);
    pk.y = bfr(vp[2]) | (bfr(vp[3])<<16);
    ((uint2*)hb)[i] = pk;
}

// ---------------- final MLP ----------------
__global__ __launch_bounds__(BLK) void final_kernel(
    const float* __restrict__ h,
    const float* __restrict__ Wf, const float* __restrict__ bf,
    const float* __restrict__ Wo, const float* __restrict__ bo,
    float* __restrict__ out)
{
    __shared__ float smem[130*SROW];
    __shared__ int s_src[TE];
    const int tid = threadIdx.x;
    const int n0 = blockIdx.x * TE;
    const int cg = tid & 15, eg = tid >> 4, c0 = cg*8;

    if (tid < TE) { int n = n0 + tid; s_src[tid] = (n < NN) ? n : NN-1; }
    __syncthreads();
    stage_rows(smem, h, s_src, tid);
    __syncthreads();

    float acc[4][8];
    #pragma unroll
    for (int j=0;j<8;++j){ float bv=bf[c0+j];
        #pragma unroll
        for (int i=0;i<4;++i) acc[i][j]=bv; }
    mv_acc(smem, HD, Wf, c0, eg, acc);
    __syncthreads();

    #pragma unroll
    for (int j=0;j<8;++j){
        float4 m0;
        m0.x=fmaxf(acc[0][j],0.f); m0.y=fmaxf(acc[1][j],0.f);
        m0.z=fmaxf(acc[2][j],0.f); m0.w=fmaxf(acc[3][j],0.f);
        *(float4*)&smem[(c0+j)*SROW + eg*4] = m0;
    }
    __syncthreads();

    const int e = tid >> 2, q = tid & 3;
    float s = 0.f;
    #pragma unroll
    for (int kk=0; kk<32; ++kk) {
        const int k = q*32 + kk;
        s = fmaf(smem[k*SROW + e], Wo[k], s);
    }
    s += __shfl_xor(s, 1);
    s += __shfl_xor(s, 2);
    const int n = n0 + e;
    if (q == 0 && n < NN)
        out[n] = sigm(s + bo[0]);
}

// ---------------- launch ----------------
extern "C" void kernel_launch(void* const* d_in, const int* in_sizes, int n_in,
                              void* d_out, int out_size, void* d_ws, size_t ws_size,
                              hipStream_t stream)
{
    const float* x    = (const float*)d_in[0];
    const float* ea   = (const float*)d_in[1];
    const int*   ei   = (const int*)d_in[2];
    const float* Win0 = (const float*)d_in[4];
    const float* bin0 = (const float*)d_in[5];
    const float* Win1 = (const float*)d_in[6];
    const float* bin1 = (const float*)d_in[7];
    const float* W1a  = (const float*)d_in[8];
    const float* b1a  = (const float*)d_in[9];
    const float* W1b  = (const float*)d_in[10];
    const float* b1b  = (const float*)d_in[11];
    const float* W2a  = (const float*)d_in[12];
    const float* b2a  = (const float*)d_in[13];
    const float* W2b  = (const float*)d_in[14];
    const float* b2b  = (const float*)d_in[15];
    const float* gmm  = (const float*)d_in[16];
    const float* bta  = (const float*)d_in[17];
    const float* Wf   = (const float*)d_in[18];
    const float* bfv  = (const float*)d_in[19];
    const float* Wo   = (const float*)d_in[20];
    const float* bo   = (const float*)d_in[21];
    float* out = (float*)d_out;

    char* p = (char*)d_ws;
    float* h     = (float*)p;  p += (size_t)NN*HD*4;
    float* rbuf  = (float*)p;  p += (size_t)NN*HD*4;
    u16*   hb    = (u16*)p;    p += (size_t)NN*HD*2;
    u16*   W1aT  = (u16*)p;    p += (size_t)3*128*160*2;
    u16*   W1bT  = (u16*)p;    p += (size_t)3*128*128*2;
    u16*   W2aT  = (u16*)p;    p += (size_t)3*128*256*2;
    u16*   W2bT  = (u16*)p;    p += (size_t)3*128*128*2;
    float* rd    = (float*)p;  p += (size_t)NN*4;
    float* bn    = (float*)p;  p += 256*4;
    int*   cnt   = (int*)p;    p += (size_t)NN*4;
    int*   fill  = (int*)p;    p += (size_t)NN*4;
    int*   off   = (int*)p;    p += (size_t)(NN+1)*4;
    int*   eidx  = (int*)p;

    const int* srcp = ei;
    const int* dstp = ei + NE;

    const int GN = (NN + TE - 1) / TE;     // 782
    const int G4 = (NN*HD/4 + 255) / 256;  // 6250

    // ---- CSR build ----
    zero_i_k<<<(2*NN+255)/256, 256, 0, stream>>>(cnt, 2*NN);
    count_k<<<(NE+255)/256, 256, 0, stream>>>(dstp, cnt);
    scan_k<<<1, 1024, 0, stream>>>(cnt, off);
    rdenom_k<<<(NN+255)/256, 256, 0, stream>>>(cnt, rd);
    fill_k<<<(NE+255)/256, 256, 0, stream>>>(dstp, off, fill, eidx);

    // ---- weight convert/transpose to bf16 [c][k] ----
    for (int l = 0; l < 3; ++l) {
        wconv_k<<<(128*160+255)/256, 256, 0, stream>>>(W1a + (size_t)l*130*128, W1aT + (size_t)l*128*160, 130, 160, 128);
        wconv_k<<<(128*128+255)/256, 256, 0, stream>>>(W1b + (size_t)l*128*128, W1bT + (size_t)l*128*128, 128, 128, 128);
        wconv_k<<<(128*256+255)/256, 256, 0, stream>>>(W2a + (size_t)l*256*128, W2aT + (size_t)l*128*256, 256, 256, 128);
        wconv_k<<<(128*128+255)/256, 256, 0, stream>>>(W2b + (size_t)l*128*128, W2bT + (size_t)l*128*128, 128, 128, 128);
    }

    input_mlp_k<<<GN, BLK, 0, stream>>>(x, Win0, bin0, Win1, bin1, h, hb);

    for (int l = 0; l < 3; ++l) {
        zero_bn_k<<<1, 256, 0, stream>>>(bn);
        edge_node_kernel<<<GN, BLK, 0, stream>>>(h, hb, ea, srcp, eidx, off, rd,
            W1aT + (size_t)l*128*160, b1a + l*HD,
            W1bT + (size_t)l*128*128, b1b + l*HD,
            W2aT + (size_t)l*128*256, b2a + l*HD,
            W2bT + (size_t)l*128*128, b2b + l*HD, rbuf);
        bn_stats_k<<<400, 256, 0, stream>>>(rbuf, bn);
        bn_norm_k<<<G4, 256, 0, stream>>>(rbuf, bn, gmm + l*HD, bta + l*HD, h, hb);
    }

    final_kernel<<<GN, BLK, 0, stream>>>(h, Wf, bfv, Wo, bo, out);
}